// Round 7
// baseline (344.714 us; speedup 1.0000x reference)
//
#include <hip/hip_runtime.h>
#include <hip/hip_fp16.h>

#define N_NODES 50000
#define N_EDGES 800000
#define NGRAPH  256
#define FDIM    64
#define EDIM    16
#define NT      (N_NODES / 16)      // 3125 node tiles (exact)
#define SH      8                   // CSR counter shards (= src octants)
#define M8      (N_NODES * SH)
#define NB8     ((M8 + 255) / 256)
#define CH8     ((NB8 + 255) / 256)

// XCD-partitioned count/fill: 8 groups (blockIdx%8 -> XCD round-robin heuristic),
// group r owns dst-range [r*NPG, (r+1)*NPG).
#define GRPS       8
#define GRP_BLOCKS 256
#define GRID_CF    (GRPS * GRP_BLOCKS)
#define NPG        ((N_NODES + GRPS - 1) / GRPS)   // 6250

// CSR shard index = src>>13 (0..6): edge lists coarsely SORTED BY SRC ->
// gather row-reads sweep the h-table low->high (better L2 residency).
#define SRC_SHARD(s) ((s) >> 13)

using half8  = __attribute__((ext_vector_type(8))) _Float16;
using float4v = __attribute__((ext_vector_type(4))) float;

__device__ __forceinline__ unsigned hmul2u(unsigned a, __half2 m) {
    __half2 r = __hmul2(__builtin_bit_cast(__half2, a), m);
    return __builtin_bit_cast(unsigned, r);
}
__device__ __forceinline__ unsigned packf2(float a, float b) {
    return __builtin_bit_cast(unsigned, __floats2half2_rn(a, b));
}

// ---------------- small setup kernels ----------------

__global__ __launch_bounds__(256) void k_count(const int* __restrict__ src,
                                               const int* __restrict__ dst,
                                               int* __restrict__ cnt8) {
    int grp = blockIdx.x & (GRPS - 1);
    int bi  = blockIdx.x >> 3;
    int lo = grp * NPG;
    int hi = lo + NPG; if (hi > N_NODES) hi = N_NODES;
    for (int e = bi * 256 + threadIdx.x; e < N_EDGES; e += GRP_BLOCKS * 256) {
        int d = dst[e];
        if (d >= lo && d < hi) atomicAdd(&cnt8[d * SH + SRC_SHARD(src[e])], 1);
    }
}

// vectorized fp32->fp16 convert: x (N*64) and edge_attr (E*16), 8 elems/thread
__global__ void k_cvt(const float* __restrict__ x, __half* __restrict__ x16,
                      const float* __restrict__ edge_attr, __half* __restrict__ ea16) {
    int t = blockIdx.x * blockDim.x + threadIdx.x;
    int stride = gridDim.x * blockDim.x;
    const float4* x4 = (const float4*)x;
    uint4* xo = (uint4*)x16;
    for (int i = t; i < N_NODES * FDIM / 8; i += stride) {
        float4 a = x4[i * 2], b = x4[i * 2 + 1];
        uint4 o;
        o.x = packf2(a.x, a.y); o.y = packf2(a.z, a.w);
        o.z = packf2(b.x, b.y); o.w = packf2(b.z, b.w);
        xo[i] = o;
    }
    const float4* e4 = (const float4*)edge_attr;
    uint4* eo = (uint4*)ea16;
    for (int i = t; i < N_EDGES * EDIM / 8; i += stride) {
        float4 a = e4[i * 2], b = e4[i * 2 + 1];
        uint4 o;
        o.x = packf2(a.x, a.y); o.y = packf2(a.z, a.w);
        o.z = packf2(b.x, b.y); o.w = packf2(b.z, b.w);
        eo[i] = o;
    }
}

__global__ void k_blksum(const int* __restrict__ cnt8, int* __restrict__ blksum) {
    __shared__ int red[4];
    int b = blockIdx.x, t = threadIdx.x;
    int idx = b * 256 + t;
    int s = (idx < M8) ? cnt8[idx] : 0;
#pragma unroll
    for (int off = 32; off > 0; off >>= 1) s += __shfl_down(s, off, 64);
    int lane = t & 63, wid = t >> 6;
    if (lane == 0) red[wid] = s;
    __syncthreads();
    if (t == 0) blksum[b] = red[0] + red[1] + red[2] + red[3];
}

__global__ void k_scanblk(const int* __restrict__ blksum, int* __restrict__ boff,
                          int* __restrict__ rowp8) {
    __shared__ int sh[256];
    int t = threadIdx.x;
    int base = t * CH8;
    int v[CH8];
    int s = 0;
#pragma unroll
    for (int i = 0; i < CH8; i++) {
        int idx = base + i;
        v[i] = (idx < NB8) ? blksum[idx] : 0;
        s += v[i];
    }
    sh[t] = s;
    __syncthreads();
    for (int off = 1; off < 256; off <<= 1) {
        int u = (t >= off) ? sh[t - off] : 0;
        __syncthreads();
        sh[t] += u;
        __syncthreads();
    }
    int run = (t == 0) ? 0 : sh[t - 1];
#pragma unroll
    for (int i = 0; i < CH8; i++) {
        int idx = base + i;
        if (idx < NB8) boff[idx] = run;
        run += v[i];
    }
    if (t == 255) rowp8[M8] = sh[255];
}

// rowp + cur init + degf (deg from within-block scan difference; 32 nodes/block)
__global__ void k_rowp(const int* __restrict__ cnt8, const int* __restrict__ boff,
                       int* __restrict__ rowp8, int* __restrict__ cur8,
                       float* __restrict__ degf) {
    __shared__ int sh[256];
    int b = blockIdx.x, t = threadIdx.x;
    int idx = b * 256 + t;
    int v = (idx < M8) ? cnt8[idx] : 0;
    sh[t] = v;
    __syncthreads();
    for (int off = 1; off < 256; off <<= 1) {
        int u = (t >= off) ? sh[t - off] : 0;
        __syncthreads();
        sh[t] += u;
        __syncthreads();
    }
    if (idx < M8) {
        int excl = sh[t] - v + boff[b];
        rowp8[idx] = excl;
        cur8[idx]  = excl;
        if ((t & 7) == 7) {
            int start = (t >= 8) ? sh[t - 8] : 0;
            degf[b * 32 + (t >> 3)] = (float)(sh[t] - start + 1);
        }
    }
}

__global__ __launch_bounds__(256) void k_fill(const int* __restrict__ src,
                                              const int* __restrict__ dst,
                                              int* __restrict__ cur8,
                                              int* __restrict__ colsrc,
                                              int* __restrict__ coledge) {
    int grp = blockIdx.x & (GRPS - 1);
    int bi  = blockIdx.x >> 3;
    int lo = grp * NPG;
    int hi = lo + NPG; if (hi > N_NODES) hi = N_NODES;
    for (int e = bi * 256 + threadIdx.x; e < N_EDGES; e += GRP_BLOCKS * 256) {
        int d = dst[e];
        if (d >= lo && d < hi) {
            int s = src[e];
            int pos = atomicAdd(&cur8[d * SH + SRC_SHARD(s)], 1);
            colsrc[pos]  = s;
            coledge[pos] = e;
        }
    }
}

// ---------------- fused gather + MFMA kernels (2 tiles / block) ----------------
// Block = 4 waves, 2 tiles of 16 nodes. Waves (2t,2t+1) each gather 8 nodes of
// tile t into shared LDS tile, one barrier, then each wave runs the MFMA for
// HALF the N-columns (nn pair). Weight fragments are STREAMED inside the kk
// loop (L1/L2-resident) to keep VGPR<=64 -> __launch_bounds__(256,8) doubles
// occupancy of the latency-bound gather phase.
#define SROW 136

// hout = relu((agg+hin | hin*deg) @ Wmh[0:128] + base)
__global__ __launch_bounds__(256, 8) void k_gmv(
    const __half* __restrict__ hin16,
    const int* __restrict__ rowp8, const int* __restrict__ colsrc,
    const __half* __restrict__ base16, const float* __restrict__ degf,
    const float* __restrict__ Wmh, __half* __restrict__ hout16) {
    __shared__ __align__(16) _Float16 S[2][16 * SROW];
    int lane = threadIdx.x & 63, wid = threadIdx.x >> 6;
    int tile = wid >> 1, h = wid & 1;
    int t = blockIdx.x * 2 + tile;
    int tb = t * 16;
    int g = lane >> 3;   // subgroup = node slot within this wave's 8 nodes
    int c = lane & 7;    // uint4 slot within row
    const uint4* h8 = (const uint4*)hin16;

    if (t < NT) {
        int m = h * 8 + g;
        int node = tb + m;
        int beg = rowp8[node * SH], end = rowp8[(node + 1) * SH];
        float a0 = 0, a1 = 0, a2 = 0, a3 = 0, a4 = 0, a5 = 0, a6 = 0, a7 = 0;
        for (int p = beg; p < end; p += 8) {
            int cidx = p + c; if (cidx > end - 1) cidx = end - 1;
            int vj = colsrc[cidx];
#pragma unroll
            for (int k = 0; k < 8; k++) {
                int j = __shfl(vj, g * 8 + k, 64);
                if (p + k < end) {
                    uint4 v = h8[(size_t)j * 8 + c];
                    float2 f0 = __half22float2(__builtin_bit_cast(__half2, v.x));
                    float2 f1 = __half22float2(__builtin_bit_cast(__half2, v.y));
                    float2 f2 = __half22float2(__builtin_bit_cast(__half2, v.z));
                    float2 f3 = __half22float2(__builtin_bit_cast(__half2, v.w));
                    a0 += f0.x; a1 += f0.y; a2 += f1.x; a3 += f1.y;
                    a4 += f2.x; a5 += f2.y; a6 += f3.x; a7 += f3.y;
                }
            }
        }
        uint4 hv = h8[(size_t)node * 8 + c];
        float dg = degf[node];
        __half dh = __float2half(dg);
        __half2 dh2 = __halves2half2(dh, dh);
        float2 f0 = __half22float2(__builtin_bit_cast(__half2, hv.x));
        float2 f1 = __half22float2(__builtin_bit_cast(__half2, hv.y));
        float2 f2 = __half22float2(__builtin_bit_cast(__half2, hv.z));
        float2 f3 = __half22float2(__builtin_bit_cast(__half2, hv.w));
        uint4 s2, s1;
        s2.x = packf2(a0 + f0.x, a1 + f0.y);
        s2.y = packf2(a2 + f1.x, a3 + f1.y);
        s2.z = packf2(a4 + f2.x, a5 + f2.y);
        s2.w = packf2(a6 + f3.x, a7 + f3.y);
        s1.x = hmul2u(hv.x, dh2); s1.y = hmul2u(hv.y, dh2);
        s1.z = hmul2u(hv.z, dh2); s1.w = hmul2u(hv.w, dh2);
        uint4* Sw = (uint4*)(&S[tile][m * SROW]);
        Sw[c]     = s2;
        Sw[8 + c] = s1;
    }
    __syncthreads();
    if (t >= NT) return;

    // MFMA: this wave handles nn = {h*2, h*2+1}; weights streamed per kk
    int n = lane & 15, quad = lane >> 4;
    float4v acc[2];
#pragma unroll
    for (int i = 0; i < 2; i++)
#pragma unroll
        for (int r = 0; r < 4; r++)
            acc[i][r] = __half2float(base16[(size_t)(tb + quad * 4 + r) * FDIM + (h * 2 + i) * 16 + n]);
    const _Float16* Sr = S[tile];
#pragma unroll
    for (int kk = 0; kk < 4; kk++) {
        half8 a = *(const half8*)(Sr + n * SROW + kk * 32 + quad * 8);
#pragma unroll
        for (int i = 0; i < 2; i++) {
            int nn = h * 2 + i;
            half8 w;
#pragma unroll
            for (int j = 0; j < 8; j++) {
                int kp = kk * 32 + quad * 8 + j;
                int krow = (kp < 64) ? (64 + kp) : (kp - 64);
                w[j] = (_Float16)Wmh[krow * FDIM + nn * 16 + n];
            }
            acc[i] = __builtin_amdgcn_mfma_f32_16x16x32_f16(a, w, acc[i], 0, 0, 0);
        }
    }
#pragma unroll
    for (int i = 0; i < 2; i++)
#pragma unroll
        for (int r = 0; r < 4; r++)
            hout16[(size_t)(tb + quad * 4 + r) * FDIM + (h * 2 + i) * 16 + n] =
                __float2half(fmaxf(acc[i][r], 0.f));
}

// sc = rowsum over n of relu((agg+hin | hin*deg) @ Wom[0:128] + obase) * Wout
__global__ __launch_bounds__(256, 8) void k_gout(
    const __half* __restrict__ hin16,
    const int* __restrict__ rowp8, const int* __restrict__ colsrc,
    const __half* __restrict__ obase16, const float* __restrict__ degf,
    const float* __restrict__ Wom, const float* __restrict__ Wout,
    float* __restrict__ sc) {
    __shared__ __align__(16) _Float16 S[2][16 * SROW];
    __shared__ float part[2][2][16];
    int lane = threadIdx.x & 63, wid = threadIdx.x >> 6;
    int tile = wid >> 1, h = wid & 1;
    int t = blockIdx.x * 2 + tile;
    int tb = t * 16;
    int g = lane >> 3;
    int c = lane & 7;
    const uint4* h8 = (const uint4*)hin16;

    if (t < NT) {
        int m = h * 8 + g;
        int node = tb + m;
        int beg = rowp8[node * SH], end = rowp8[(node + 1) * SH];
        float a0 = 0, a1 = 0, a2 = 0, a3 = 0, a4 = 0, a5 = 0, a6 = 0, a7 = 0;
        for (int p = beg; p < end; p += 8) {
            int cidx = p + c; if (cidx > end - 1) cidx = end - 1;
            int vj = colsrc[cidx];
#pragma unroll
            for (int k = 0; k < 8; k++) {
                int j = __shfl(vj, g * 8 + k, 64);
                if (p + k < end) {
                    uint4 v = h8[(size_t)j * 8 + c];
                    float2 f0 = __half22float2(__builtin_bit_cast(__half2, v.x));
                    float2 f1 = __half22float2(__builtin_bit_cast(__half2, v.y));
                    float2 f2 = __half22float2(__builtin_bit_cast(__half2, v.z));
                    float2 f3 = __half22float2(__builtin_bit_cast(__half2, v.w));
                    a0 += f0.x; a1 += f0.y; a2 += f1.x; a3 += f1.y;
                    a4 += f2.x; a5 += f2.y; a6 += f3.x; a7 += f3.y;
                }
            }
        }
        uint4 hv = h8[(size_t)node * 8 + c];
        float dg = degf[node];
        __half dh = __float2half(dg);
        __half2 dh2 = __halves2half2(dh, dh);
        float2 f0 = __half22float2(__builtin_bit_cast(__half2, hv.x));
        float2 f1 = __half22float2(__builtin_bit_cast(__half2, hv.y));
        float2 f2 = __half22float2(__builtin_bit_cast(__half2, hv.z));
        float2 f3 = __half22float2(__builtin_bit_cast(__half2, hv.w));
        uint4 s2, s1;
        s2.x = packf2(a0 + f0.x, a1 + f0.y);
        s2.y = packf2(a2 + f1.x, a3 + f1.y);
        s2.z = packf2(a4 + f2.x, a5 + f2.y);
        s2.w = packf2(a6 + f3.x, a7 + f3.y);
        s1.x = hmul2u(hv.x, dh2); s1.y = hmul2u(hv.y, dh2);
        s1.z = hmul2u(hv.z, dh2); s1.w = hmul2u(hv.w, dh2);
        uint4* Sw = (uint4*)(&S[tile][m * SROW]);
        Sw[c]     = s2;
        Sw[8 + c] = s1;
    }
    __syncthreads();

    int n = lane & 15, quad = lane >> 4;
    if (t < NT) {
        float wo0 = Wout[(h * 2 + 0) * 16 + n];
        float wo1 = Wout[(h * 2 + 1) * 16 + n];
        float4v acc[2];
#pragma unroll
        for (int i = 0; i < 2; i++)
#pragma unroll
            for (int r = 0; r < 4; r++)
                acc[i][r] = __half2float(obase16[(size_t)(tb + quad * 4 + r) * FDIM + (h * 2 + i) * 16 + n]);
        const _Float16* Sr = S[tile];
#pragma unroll
        for (int kk = 0; kk < 4; kk++) {
            half8 a = *(const half8*)(Sr + n * SROW + kk * 32 + quad * 8);
#pragma unroll
            for (int i = 0; i < 2; i++) {
                int nn = h * 2 + i;
                half8 w;
#pragma unroll
                for (int j = 0; j < 8; j++) {
                    int kp = kk * 32 + quad * 8 + j;
                    int krow = (kp < 64) ? (64 + kp) : (kp - 64);
                    w[j] = (_Float16)Wom[krow * FDIM + nn * 16 + n];
                }
                acc[i] = __builtin_amdgcn_mfma_f32_16x16x32_f16(a, w, acc[i], 0, 0, 0);
            }
        }
#pragma unroll
        for (int r = 0; r < 4; r++) {
            float s = fmaxf(acc[0][r], 0.f) * wo0 + fmaxf(acc[1][r], 0.f) * wo1;
            s += __shfl_xor(s, 1, 64);
            s += __shfl_xor(s, 2, 64);
            s += __shfl_xor(s, 4, 64);
            s += __shfl_xor(s, 8, 64);
            if (n == 0) part[tile][h][quad * 4 + r] = s;
        }
    }
    __syncthreads();
    if (t < NT && h == 0 && lane < 16)
        sc[tb + lane] = part[tile][0][lane] + part[tile][1][lane];
}

// Fused gather(x16) + ea16 gather (fp16, L3-resident) + obase MFMA:
// obase = (aggX + x) @ Wom[128:192] + bom.
#define SROW2 72
__global__ __launch_bounds__(256, 8) void k_gxob(
    const __half* __restrict__ x16, const __half* __restrict__ ea16,
    const int* __restrict__ rowp8, const int* __restrict__ colsrc,
    const int* __restrict__ coledge,
    const float* __restrict__ Wom, const float* __restrict__ bom,
    __half* __restrict__ obase16, float* __restrict__ ea) {
    __shared__ __align__(16) _Float16 S[2][16 * SROW2];
    int lane = threadIdx.x & 63, wid = threadIdx.x >> 6;
    int tile = wid >> 1, h = wid & 1;
    int t = blockIdx.x * 2 + tile;
    int tb = t * 16;
    int g = lane >> 3;
    int c = lane & 7;
    const uint4* h8 = (const uint4*)x16;
    const unsigned* eap = (const unsigned*)ea16;   // edge row = 8 x uint (2 halves)

    if (t < NT) {
        int m = h * 8 + g;
        int node = tb + m;
        int beg = rowp8[node * SH], end = rowp8[(node + 1) * SH];
        float a0 = 0, a1 = 0, a2 = 0, a3 = 0, a4 = 0, a5 = 0, a6 = 0, a7 = 0;
        float x0 = 0.f, x1 = 0.f;
        for (int p = beg; p < end; p += 8) {
            int cidx = p + c; if (cidx > end - 1) cidx = end - 1;
            int vs = colsrc[cidx];
            int ve = coledge[cidx];
#pragma unroll
            for (int k = 0; k < 8; k++) {
                int j = __shfl(vs, g * 8 + k, 64);
                int e = __shfl(ve, g * 8 + k, 64);
                if (p + k < end) {
                    uint4 v = h8[(size_t)j * 8 + c];
                    unsigned w = eap[(size_t)e * 8 + c];
                    float2 wf = __half22float2(__builtin_bit_cast(__half2, w));
                    float2 f0 = __half22float2(__builtin_bit_cast(__half2, v.x));
                    float2 f1 = __half22float2(__builtin_bit_cast(__half2, v.y));
                    float2 f2 = __half22float2(__builtin_bit_cast(__half2, v.z));
                    float2 f3 = __half22float2(__builtin_bit_cast(__half2, v.w));
                    a0 += f0.x; a1 += f0.y; a2 += f1.x; a3 += f1.y;
                    a4 += f2.x; a5 += f2.y; a6 += f3.x; a7 += f3.y;
                    x0 += wf.x; x1 += wf.y;
                }
            }
        }
        uint4 xv = h8[(size_t)node * 8 + c];
        float2 f0 = __half22float2(__builtin_bit_cast(__half2, xv.x));
        float2 f1 = __half22float2(__builtin_bit_cast(__half2, xv.y));
        float2 f2 = __half22float2(__builtin_bit_cast(__half2, xv.z));
        float2 f3 = __half22float2(__builtin_bit_cast(__half2, xv.w));
        uint4 sA;
        sA.x = packf2(a0 + f0.x, a1 + f0.y);
        sA.y = packf2(a2 + f1.x, a3 + f1.y);
        sA.z = packf2(a4 + f2.x, a5 + f2.y);
        sA.w = packf2(a6 + f3.x, a7 + f3.y);
        ((uint4*)(&S[tile][m * SROW2]))[c] = sA;
        ((float2*)ea)[(size_t)node * 8 + c] = make_float2(x0, x1);
    }
    __syncthreads();
    if (t >= NT) return;

    int n = lane & 15, quad = lane >> 4;
    float4v acc[2];
#pragma unroll
    for (int i = 0; i < 2; i++) {
        float b = bom[(h * 2 + i) * 16 + n];
#pragma unroll
        for (int r = 0; r < 4; r++) acc[i][r] = b;
    }
    const _Float16* Sr = S[tile];
#pragma unroll
    for (int kk = 0; kk < 2; kk++) {
        half8 a = *(const half8*)(Sr + n * SROW2 + kk * 32 + quad * 8);
#pragma unroll
        for (int i = 0; i < 2; i++) {
            int nn = h * 2 + i;
            half8 w;
#pragma unroll
            for (int j = 0; j < 8; j++) {
                int kp = kk * 32 + quad * 8 + j;
                w[j] = (_Float16)Wom[(128 + kp) * FDIM + nn * 16 + n];
            }
            acc[i] = __builtin_amdgcn_mfma_f32_16x16x32_f16(a, w, acc[i], 0, 0, 0);
        }
    }
#pragma unroll
    for (int i = 0; i < 2; i++)
#pragma unroll
        for (int r = 0; r < 4; r++)
            obase16[(size_t)(tb + quad * 4 + r) * FDIM + (h * 2 + i) * 16 + n] =
                __float2half(acc[i][r]);
}

// ---------------- h0/base (VALU, reads fp32 x once) ----------------
__global__ void k_h0base(const float* __restrict__ x, const float* __restrict__ ea,
                         const float* __restrict__ Wnh, const float* __restrict__ bnh,
                         const float* __restrict__ Wmh, const float* __restrict__ bmh,
                         __half* __restrict__ h0out16, __half* __restrict__ base16) {
    __shared__ __align__(16) float sx[4][FDIM];
    __shared__ __align__(16) float sea[4][EDIM];
    int lane = threadIdx.x & 63;
    int wid  = threadIdx.x >> 6;
    float wnh[FDIM], w3[EDIM];
#pragma unroll
    for (int m = 0; m < FDIM; m++) wnh[m] = Wnh[m * FDIM + lane];
    float csum = 0.f;
#pragma unroll
    for (int m = 0; m < EDIM; m++) {
        w3[m] = Wmh[(2 * FDIM + m) * FDIM + lane];
        csum += w3[m];
    }
    float bnhk = bnh[lane], bmhk = bmh[lane];
    int gw = blockIdx.x * 4 + wid;
    int nw = gridDim.x * 4;
    for (int i = gw; i < N_NODES; i += nw) {
        sx[wid][lane] = x[i * FDIM + lane];
        if (lane < EDIM) sea[wid][lane] = ea[i * EDIM + lane];
        float acc0 = bnhk, acc1 = 0.f, acc2 = 0.f, acc3 = 0.f;
        const float4* s4 = (const float4*)sx[wid];
#pragma unroll
        for (int m4 = 0; m4 < FDIM / 4; m4++) {
            float4 v = s4[m4];
            acc0 = fmaf(v.x, wnh[4 * m4 + 0], acc0);
            acc1 = fmaf(v.y, wnh[4 * m4 + 1], acc1);
            acc2 = fmaf(v.z, wnh[4 * m4 + 2], acc2);
            acc3 = fmaf(v.w, wnh[4 * m4 + 3], acc3);
        }
        float h0 = fmaxf((acc0 + acc2) + (acc1 + acc3), 0.f);
        float b0 = h0 + bmhk + csum, b1 = 0.f, b2 = 0.f, b3 = 0.f;
        const float4* e4 = (const float4*)sea[wid];
#pragma unroll
        for (int m4 = 0; m4 < EDIM / 4; m4++) {
            float4 v = e4[m4];
            b0 = fmaf(v.x, w3[4 * m4 + 0], b0);
            b1 = fmaf(v.y, w3[4 * m4 + 1], b1);
            b2 = fmaf(v.z, w3[4 * m4 + 2], b2);
            b3 = fmaf(v.w, w3[4 * m4 + 3], b3);
        }
        h0out16[i * FDIM + lane] = __float2half(h0);
        base16[i * FDIM + lane]  = __float2half((b0 + b2) + (b1 + b3));
    }
}

// out[g] = sum of sc over graph-g nodes + b_out
__global__ void k_pool(const float* __restrict__ sc, const int* __restrict__ batch,
                       const float* __restrict__ b_out, float* __restrict__ out) {
    __shared__ float red[4];
    int g = blockIdx.x, t = threadIdx.x;
    int lo = 0, hi = N_NODES;
    while (lo < hi) { int mid = (lo + hi) >> 1; if (batch[mid] < g) lo = mid + 1; else hi = mid; }
    int lo2 = lo, hi2 = N_NODES;
    while (lo2 < hi2) { int mid = (lo2 + hi2) >> 1; if (batch[mid] < g + 1) lo2 = mid + 1; else hi2 = mid; }
    float s = 0.f;
    for (int i = lo + t; i < lo2; i += 256) s += sc[i];
#pragma unroll
    for (int off = 32; off > 0; off >>= 1) s += __shfl_down(s, off, 64);
    int lane = t & 63, wid = t >> 6;
    if (lane == 0) red[wid] = s;
    __syncthreads();
    if (t == 0) out[g] = red[0] + red[1] + red[2] + red[3] + b_out[0];
}

// ---------------- launcher ----------------

extern "C" void kernel_launch(void* const* d_in, const int* in_sizes, int n_in,
                              void* d_out, int out_size, void* d_ws, size_t ws_size,
                              hipStream_t stream) {
    const float* x         = (const float*)d_in[0];
    const float* edge_attr = (const float*)d_in[1];
    const float* Wnh       = (const float*)d_in[2];
    const float* bnh       = (const float*)d_in[3];
    const float* Wmh       = (const float*)d_in[4];
    const float* bmh       = (const float*)d_in[5];
    const float* Wom       = (const float*)d_in[6];
    const float* bom       = (const float*)d_in[7];
    const float* Wout      = (const float*)d_in[8];
    const float* bout      = (const float*)d_in[9];
    const int*   eidx      = (const int*)d_in[10];
    const int*   batch     = (const int*)d_in[11];
    const int*   srcI = eidx;
    const int*   dstI = eidx + N_EDGES;
    float* out = (float*)d_out;
    (void)in_sizes; (void)n_in; (void)out_size;

    char* w = (char*)d_ws;
    size_t off = 0;
    auto take = [&](size_t b) -> void* {
        void* p = w + off;
        off = (off + b + 255) & ~(size_t)255;
        return p;
    };
    float*  ea     = (float*)take((size_t)N_NODES * EDIM * 4);
    int*    cnt8   = (int*)take((size_t)M8 * 4);
    int*    rowp8  = (int*)take((size_t)(M8 + 1) * 4);
    int*    cur8   = (int*)take((size_t)M8 * 4);
    float*  degf   = (float*)take((size_t)N_NODES * 4);
    int*    colsrc = (int*)take((size_t)N_EDGES * 4);
    int*    coledge= (int*)take((size_t)N_EDGES * 4);
    __half* ea16   = (__half*)take((size_t)N_EDGES * EDIM * 2);
    float*  sc     = (float*)take((size_t)N_NODES * 4);
    int*    blks   = (int*)take((size_t)NB8 * 4);
    int*    boff   = (int*)take((size_t)NB8 * 4);
    __half* x16    = (__half*)take((size_t)N_NODES * FDIM * 2);
    __half* hA16   = (__half*)take((size_t)N_NODES * FDIM * 2);
    __half* hB16   = (__half*)take((size_t)N_NODES * FDIM * 2);
    __half* base16 = (__half*)take((size_t)N_NODES * FDIM * 2);
    __half* obase16= (__half*)take((size_t)N_NODES * FDIM * 2);
    (void)ws_size;

    const int G2 = (NT + 1) / 2;   // 1563 blocks; 4 waves, 2 tiles each

    hipMemsetAsync(cnt8, 0, (size_t)M8 * 4, stream);
    k_count<<<GRID_CF, 256, 0, stream>>>(srcI, dstI, cnt8);
    k_cvt<<<2048, 256, 0, stream>>>(x, x16, edge_attr, ea16);
    k_blksum<<<NB8, 256, 0, stream>>>(cnt8, blks);
    k_scanblk<<<1, 256, 0, stream>>>(blks, boff, rowp8);
    k_rowp<<<NB8, 256, 0, stream>>>(cnt8, boff, rowp8, cur8, degf);
    k_fill<<<GRID_CF, 256, 0, stream>>>(srcI, dstI, cur8, colsrc, coledge);

    k_gxob<<<G2, 256, 0, stream>>>(x16, ea16, rowp8, colsrc, coledge,
                                   Wom, bom, obase16, ea);
    k_h0base<<<2048, 256, 0, stream>>>(x, ea, Wnh, bnh, Wmh, bmh, hA16, base16);

    k_gmv<<<G2, 256, 0, stream>>>(hA16, rowp8, colsrc, base16, degf, Wmh, hB16);
    k_gmv<<<G2, 256, 0, stream>>>(hB16, rowp8, colsrc, base16, degf, Wmh, hA16);
    k_gmv<<<G2, 256, 0, stream>>>(hA16, rowp8, colsrc, base16, degf, Wmh, hB16);

    k_gout<<<G2, 256, 0, stream>>>(hB16, rowp8, colsrc, obase16, degf, Wom, Wout, sc);
    k_pool<<<NGRAPH, 256, 0, stream>>>(sc, batch, bout, out);
}

// Round 8
// 336.524 us; speedup vs baseline: 1.0243x; 1.0243x over previous
//
#include <hip/hip_runtime.h>
#include <hip/hip_fp16.h>

#define N_NODES 50000
#define N_EDGES 800000
#define NGRAPH  256
#define FDIM    64
#define EDIM    16
#define NT      (N_NODES / 16)      // 3125 node tiles (exact)
#define SH      8                   // CSR counter shards (= src octants)
#define M8      (N_NODES * SH)
#define NB8     ((M8 + 255) / 256)
#define CH8     ((NB8 + 255) / 256)

// XCD-partitioned count/fill: 8 groups (blockIdx%8 -> XCD round-robin heuristic),
// group r owns dst-range [r*NPG, (r+1)*NPG).
#define GRPS       8
#define GRP_BLOCKS 256
#define GRID_CF    (GRPS * GRP_BLOCKS)
#define NPG        ((N_NODES + GRPS - 1) / GRPS)   // 6250

// CSR shard index = src>>13 (0..6): edge lists coarsely SORTED BY SRC ->
// gather row-reads sweep the h-table low->high (better L2 residency).
#define SRC_SHARD(s) ((s) >> 13)

using half8  = __attribute__((ext_vector_type(8))) _Float16;
using float4v = __attribute__((ext_vector_type(4))) float;

__device__ __forceinline__ unsigned hmul2u(unsigned a, __half2 m) {
    __half2 r = __hmul2(__builtin_bit_cast(__half2, a), m);
    return __builtin_bit_cast(unsigned, r);
}
__device__ __forceinline__ unsigned packf2(float a, float b) {
    return __builtin_bit_cast(unsigned, __floats2half2_rn(a, b));
}

// ---------------- small setup kernels ----------------

__global__ __launch_bounds__(256) void k_count(const int* __restrict__ src,
                                               const int* __restrict__ dst,
                                               int* __restrict__ cnt8) {
    int grp = blockIdx.x & (GRPS - 1);
    int bi  = blockIdx.x >> 3;
    int lo = grp * NPG;
    int hi = lo + NPG; if (hi > N_NODES) hi = N_NODES;
    for (int e = bi * 256 + threadIdx.x; e < N_EDGES; e += GRP_BLOCKS * 256) {
        int d = dst[e];
        if (d >= lo && d < hi) atomicAdd(&cnt8[d * SH + SRC_SHARD(src[e])], 1);
    }
}

// vectorized fp32->fp16 convert: x (N*64) and edge_attr (E*16), 8 elems/thread
__global__ void k_cvt(const float* __restrict__ x, __half* __restrict__ x16,
                      const float* __restrict__ edge_attr, __half* __restrict__ ea16) {
    int t = blockIdx.x * blockDim.x + threadIdx.x;
    int stride = gridDim.x * blockDim.x;
    const float4* x4 = (const float4*)x;
    uint4* xo = (uint4*)x16;
    for (int i = t; i < N_NODES * FDIM / 8; i += stride) {
        float4 a = x4[i * 2], b = x4[i * 2 + 1];
        uint4 o;
        o.x = packf2(a.x, a.y); o.y = packf2(a.z, a.w);
        o.z = packf2(b.x, b.y); o.w = packf2(b.z, b.w);
        xo[i] = o;
    }
    const float4* e4 = (const float4*)edge_attr;
    uint4* eo = (uint4*)ea16;
    for (int i = t; i < N_EDGES * EDIM / 8; i += stride) {
        float4 a = e4[i * 2], b = e4[i * 2 + 1];
        uint4 o;
        o.x = packf2(a.x, a.y); o.y = packf2(a.z, a.w);
        o.z = packf2(b.x, b.y); o.w = packf2(b.z, b.w);
        eo[i] = o;
    }
}

__global__ void k_blksum(const int* __restrict__ cnt8, int* __restrict__ blksum) {
    __shared__ int red[4];
    int b = blockIdx.x, t = threadIdx.x;
    int idx = b * 256 + t;
    int s = (idx < M8) ? cnt8[idx] : 0;
#pragma unroll
    for (int off = 32; off > 0; off >>= 1) s += __shfl_down(s, off, 64);
    int lane = t & 63, wid = t >> 6;
    if (lane == 0) red[wid] = s;
    __syncthreads();
    if (t == 0) blksum[b] = red[0] + red[1] + red[2] + red[3];
}

__global__ void k_scanblk(const int* __restrict__ blksum, int* __restrict__ boff,
                          int* __restrict__ rowp8) {
    __shared__ int sh[256];
    int t = threadIdx.x;
    int base = t * CH8;
    int v[CH8];
    int s = 0;
#pragma unroll
    for (int i = 0; i < CH8; i++) {
        int idx = base + i;
        v[i] = (idx < NB8) ? blksum[idx] : 0;
        s += v[i];
    }
    sh[t] = s;
    __syncthreads();
    for (int off = 1; off < 256; off <<= 1) {
        int u = (t >= off) ? sh[t - off] : 0;
        __syncthreads();
        sh[t] += u;
        __syncthreads();
    }
    int run = (t == 0) ? 0 : sh[t - 1];
#pragma unroll
    for (int i = 0; i < CH8; i++) {
        int idx = base + i;
        if (idx < NB8) boff[idx] = run;
        run += v[i];
    }
    if (t == 255) rowp8[M8] = sh[255];
}

// rowp + cur init + degf (deg from within-block scan difference; 32 nodes/block)
__global__ void k_rowp(const int* __restrict__ cnt8, const int* __restrict__ boff,
                       int* __restrict__ rowp8, int* __restrict__ cur8,
                       float* __restrict__ degf) {
    __shared__ int sh[256];
    int b = blockIdx.x, t = threadIdx.x;
    int idx = b * 256 + t;
    int v = (idx < M8) ? cnt8[idx] : 0;
    sh[t] = v;
    __syncthreads();
    for (int off = 1; off < 256; off <<= 1) {
        int u = (t >= off) ? sh[t - off] : 0;
        __syncthreads();
        sh[t] += u;
        __syncthreads();
    }
    if (idx < M8) {
        int excl = sh[t] - v + boff[b];
        rowp8[idx] = excl;
        cur8[idx]  = excl;
        if ((t & 7) == 7) {
            int start = (t >= 8) ? sh[t - 8] : 0;
            degf[b * 32 + (t >> 3)] = (float)(sh[t] - start + 1);
        }
    }
}

__global__ __launch_bounds__(256) void k_fill(const int* __restrict__ src,
                                              const int* __restrict__ dst,
                                              int* __restrict__ cur8,
                                              int* __restrict__ colsrc,
                                              int* __restrict__ coledge) {
    int grp = blockIdx.x & (GRPS - 1);
    int bi  = blockIdx.x >> 3;
    int lo = grp * NPG;
    int hi = lo + NPG; if (hi > N_NODES) hi = N_NODES;
    for (int e = bi * 256 + threadIdx.x; e < N_EDGES; e += GRP_BLOCKS * 256) {
        int d = dst[e];
        if (d >= lo && d < hi) {
            int s = src[e];
            int pos = atomicAdd(&cur8[d * SH + SRC_SHARD(s)], 1);
            colsrc[pos]  = s;
            coledge[pos] = e;
        }
    }
}

// ---------------- fused gather + MFMA kernels (2 tiles / block) ----------------
// Block = 4 waves, 2 tiles of 16 nodes. Waves (2t,2t+1) each gather 8 nodes of
// tile t into shared LDS tile, one barrier, then each wave runs the MFMA for
// HALF the N-columns (nn pair) with PRE-LOADED weight fragments (loaded during
// the gather-latency shadow; streaming them per-kk regressed in R7).
#define SROW 136

// hout = relu((agg+hin | hin*deg) @ Wmh[0:128] + base)
__global__ __launch_bounds__(256, 4) void k_gmv(
    const __half* __restrict__ hin16,
    const int* __restrict__ rowp8, const int* __restrict__ colsrc,
    const __half* __restrict__ base16, const float* __restrict__ degf,
    const float* __restrict__ Wmh, __half* __restrict__ hout16) {
    __shared__ __align__(16) _Float16 S[2][16 * SROW];
    int lane = threadIdx.x & 63, wid = threadIdx.x >> 6;
    int tile = wid >> 1, h = wid & 1;
    int t = blockIdx.x * 2 + tile;
    int tb = t * 16;
    int g = lane >> 3;   // subgroup = node slot within this wave's 8 nodes
    int c = lane & 7;    // uint4 slot within row
    const uint4* h8 = (const uint4*)hin16;

    if (t < NT) {
        int m = h * 8 + g;
        int node = tb + m;
        int beg = rowp8[node * SH], end = rowp8[(node + 1) * SH];
        float a0 = 0, a1 = 0, a2 = 0, a3 = 0, a4 = 0, a5 = 0, a6 = 0, a7 = 0;
        for (int p = beg; p < end; p += 8) {
            int cidx = p + c; if (cidx > end - 1) cidx = end - 1;
            int vj = colsrc[cidx];
#pragma unroll
            for (int k = 0; k < 8; k++) {
                int j = __shfl(vj, g * 8 + k, 64);
                if (p + k < end) {
                    uint4 v = h8[(size_t)j * 8 + c];
                    float2 f0 = __half22float2(__builtin_bit_cast(__half2, v.x));
                    float2 f1 = __half22float2(__builtin_bit_cast(__half2, v.y));
                    float2 f2 = __half22float2(__builtin_bit_cast(__half2, v.z));
                    float2 f3 = __half22float2(__builtin_bit_cast(__half2, v.w));
                    a0 += f0.x; a1 += f0.y; a2 += f1.x; a3 += f1.y;
                    a4 += f2.x; a5 += f2.y; a6 += f3.x; a7 += f3.y;
                }
            }
        }
        uint4 hv = h8[(size_t)node * 8 + c];
        float dg = degf[node];
        __half dh = __float2half(dg);
        __half2 dh2 = __halves2half2(dh, dh);
        float2 f0 = __half22float2(__builtin_bit_cast(__half2, hv.x));
        float2 f1 = __half22float2(__builtin_bit_cast(__half2, hv.y));
        float2 f2 = __half22float2(__builtin_bit_cast(__half2, hv.z));
        float2 f3 = __half22float2(__builtin_bit_cast(__half2, hv.w));
        uint4 s2, s1;
        s2.x = packf2(a0 + f0.x, a1 + f0.y);
        s2.y = packf2(a2 + f1.x, a3 + f1.y);
        s2.z = packf2(a4 + f2.x, a5 + f2.y);
        s2.w = packf2(a6 + f3.x, a7 + f3.y);
        s1.x = hmul2u(hv.x, dh2); s1.y = hmul2u(hv.y, dh2);
        s1.z = hmul2u(hv.z, dh2); s1.w = hmul2u(hv.w, dh2);
        uint4* Sw = (uint4*)(&S[tile][m * SROW]);
        Sw[c]     = s2;
        Sw[8 + c] = s1;
    }
    __syncthreads();
    if (t >= NT) return;

    // MFMA: this wave handles nn = {h*2, h*2+1}
    int n = lane & 15, quad = lane >> 4;
    half8 bfr[4][2];
#pragma unroll
    for (int kk = 0; kk < 4; kk++)
#pragma unroll
        for (int i = 0; i < 2; i++) {
            int nn = h * 2 + i;
            half8 tmp;
#pragma unroll
            for (int j = 0; j < 8; j++) {
                int kp = kk * 32 + quad * 8 + j;
                int krow = (kp < 64) ? (64 + kp) : (kp - 64);
                tmp[j] = (_Float16)Wmh[krow * FDIM + nn * 16 + n];
            }
            bfr[kk][i] = tmp;
        }
    float4v acc[2];
#pragma unroll
    for (int i = 0; i < 2; i++)
#pragma unroll
        for (int r = 0; r < 4; r++)
            acc[i][r] = __half2float(base16[(size_t)(tb + quad * 4 + r) * FDIM + (h * 2 + i) * 16 + n]);
    const _Float16* Sr = S[tile];
#pragma unroll
    for (int kk = 0; kk < 4; kk++) {
        half8 a = *(const half8*)(Sr + n * SROW + kk * 32 + quad * 8);
#pragma unroll
        for (int i = 0; i < 2; i++)
            acc[i] = __builtin_amdgcn_mfma_f32_16x16x32_f16(a, bfr[kk][i], acc[i], 0, 0, 0);
    }
#pragma unroll
    for (int i = 0; i < 2; i++)
#pragma unroll
        for (int r = 0; r < 4; r++)
            hout16[(size_t)(tb + quad * 4 + r) * FDIM + (h * 2 + i) * 16 + n] =
                __float2half(fmaxf(acc[i][r], 0.f));
}

// sc = rowsum over n of relu((agg+hin | hin*deg) @ Wom[0:128] + obase) * Wout
__global__ __launch_bounds__(256, 4) void k_gout(
    const __half* __restrict__ hin16,
    const int* __restrict__ rowp8, const int* __restrict__ colsrc,
    const __half* __restrict__ obase16, const float* __restrict__ degf,
    const float* __restrict__ Wom, const float* __restrict__ Wout,
    float* __restrict__ sc) {
    __shared__ __align__(16) _Float16 S[2][16 * SROW];
    __shared__ float part[2][2][16];
    int lane = threadIdx.x & 63, wid = threadIdx.x >> 6;
    int tile = wid >> 1, h = wid & 1;
    int t = blockIdx.x * 2 + tile;
    int tb = t * 16;
    int g = lane >> 3;
    int c = lane & 7;
    const uint4* h8 = (const uint4*)hin16;

    if (t < NT) {
        int m = h * 8 + g;
        int node = tb + m;
        int beg = rowp8[node * SH], end = rowp8[(node + 1) * SH];
        float a0 = 0, a1 = 0, a2 = 0, a3 = 0, a4 = 0, a5 = 0, a6 = 0, a7 = 0;
        for (int p = beg; p < end; p += 8) {
            int cidx = p + c; if (cidx > end - 1) cidx = end - 1;
            int vj = colsrc[cidx];
#pragma unroll
            for (int k = 0; k < 8; k++) {
                int j = __shfl(vj, g * 8 + k, 64);
                if (p + k < end) {
                    uint4 v = h8[(size_t)j * 8 + c];
                    float2 f0 = __half22float2(__builtin_bit_cast(__half2, v.x));
                    float2 f1 = __half22float2(__builtin_bit_cast(__half2, v.y));
                    float2 f2 = __half22float2(__builtin_bit_cast(__half2, v.z));
                    float2 f3 = __half22float2(__builtin_bit_cast(__half2, v.w));
                    a0 += f0.x; a1 += f0.y; a2 += f1.x; a3 += f1.y;
                    a4 += f2.x; a5 += f2.y; a6 += f3.x; a7 += f3.y;
                }
            }
        }
        uint4 hv = h8[(size_t)node * 8 + c];
        float dg = degf[node];
        __half dh = __float2half(dg);
        __half2 dh2 = __halves2half2(dh, dh);
        float2 f0 = __half22float2(__builtin_bit_cast(__half2, hv.x));
        float2 f1 = __half22float2(__builtin_bit_cast(__half2, hv.y));
        float2 f2 = __half22float2(__builtin_bit_cast(__half2, hv.z));
        float2 f3 = __half22float2(__builtin_bit_cast(__half2, hv.w));
        uint4 s2, s1;
        s2.x = packf2(a0 + f0.x, a1 + f0.y);
        s2.y = packf2(a2 + f1.x, a3 + f1.y);
        s2.z = packf2(a4 + f2.x, a5 + f2.y);
        s2.w = packf2(a6 + f3.x, a7 + f3.y);
        s1.x = hmul2u(hv.x, dh2); s1.y = hmul2u(hv.y, dh2);
        s1.z = hmul2u(hv.z, dh2); s1.w = hmul2u(hv.w, dh2);
        uint4* Sw = (uint4*)(&S[tile][m * SROW]);
        Sw[c]     = s2;
        Sw[8 + c] = s1;
    }
    __syncthreads();

    int n = lane & 15, quad = lane >> 4;
    if (t < NT) {
        half8 bfr[4][2];
#pragma unroll
        for (int kk = 0; kk < 4; kk++)
#pragma unroll
            for (int i = 0; i < 2; i++) {
                int nn = h * 2 + i;
                half8 tmp;
#pragma unroll
                for (int j = 0; j < 8; j++) {
                    int kp = kk * 32 + quad * 8 + j;
                    int krow = (kp < 64) ? (64 + kp) : (kp - 64);
                    tmp[j] = (_Float16)Wom[krow * FDIM + nn * 16 + n];
                }
                bfr[kk][i] = tmp;
            }
        float wo0 = Wout[(h * 2 + 0) * 16 + n];
        float wo1 = Wout[(h * 2 + 1) * 16 + n];
        float4v acc[2];
#pragma unroll
        for (int i = 0; i < 2; i++)
#pragma unroll
            for (int r = 0; r < 4; r++)
                acc[i][r] = __half2float(obase16[(size_t)(tb + quad * 4 + r) * FDIM + (h * 2 + i) * 16 + n]);
        const _Float16* Sr = S[tile];
#pragma unroll
        for (int kk = 0; kk < 4; kk++) {
            half8 a = *(const half8*)(Sr + n * SROW + kk * 32 + quad * 8);
#pragma unroll
            for (int i = 0; i < 2; i++)
                acc[i] = __builtin_amdgcn_mfma_f32_16x16x32_f16(a, bfr[kk][i], acc[i], 0, 0, 0);
        }
#pragma unroll
        for (int r = 0; r < 4; r++) {
            float s = fmaxf(acc[0][r], 0.f) * wo0 + fmaxf(acc[1][r], 0.f) * wo1;
            s += __shfl_xor(s, 1, 64);
            s += __shfl_xor(s, 2, 64);
            s += __shfl_xor(s, 4, 64);
            s += __shfl_xor(s, 8, 64);
            if (n == 0) part[tile][h][quad * 4 + r] = s;
        }
    }
    __syncthreads();
    if (t < NT && h == 0 && lane < 16)
        sc[tb + lane] = part[tile][0][lane] + part[tile][1][lane];
}

// Fused gather(x16) + ea16 gather (fp16, L3-resident) + obase MFMA:
// obase = (aggX + x) @ Wom[128:192] + bom.
#define SROW2 72
__global__ __launch_bounds__(256, 4) void k_gxob(
    const __half* __restrict__ x16, const __half* __restrict__ ea16,
    const int* __restrict__ rowp8, const int* __restrict__ colsrc,
    const int* __restrict__ coledge,
    const float* __restrict__ Wom, const float* __restrict__ bom,
    __half* __restrict__ obase16, float* __restrict__ ea) {
    __shared__ __align__(16) _Float16 S[2][16 * SROW2];
    int lane = threadIdx.x & 63, wid = threadIdx.x >> 6;
    int tile = wid >> 1, h = wid & 1;
    int t = blockIdx.x * 2 + tile;
    int tb = t * 16;
    int g = lane >> 3;
    int c = lane & 7;
    const uint4* h8 = (const uint4*)x16;
    const unsigned* eap = (const unsigned*)ea16;   // edge row = 8 x uint (2 halves)

    if (t < NT) {
        int m = h * 8 + g;
        int node = tb + m;
        int beg = rowp8[node * SH], end = rowp8[(node + 1) * SH];
        float a0 = 0, a1 = 0, a2 = 0, a3 = 0, a4 = 0, a5 = 0, a6 = 0, a7 = 0;
        float x0 = 0.f, x1 = 0.f;
        for (int p = beg; p < end; p += 8) {
            int cidx = p + c; if (cidx > end - 1) cidx = end - 1;
            int vs = colsrc[cidx];
            int ve = coledge[cidx];
#pragma unroll
            for (int k = 0; k < 8; k++) {
                int j = __shfl(vs, g * 8 + k, 64);
                int e = __shfl(ve, g * 8 + k, 64);
                if (p + k < end) {
                    uint4 v = h8[(size_t)j * 8 + c];
                    unsigned w = eap[(size_t)e * 8 + c];
                    float2 wf = __half22float2(__builtin_bit_cast(__half2, w));
                    float2 f0 = __half22float2(__builtin_bit_cast(__half2, v.x));
                    float2 f1 = __half22float2(__builtin_bit_cast(__half2, v.y));
                    float2 f2 = __half22float2(__builtin_bit_cast(__half2, v.z));
                    float2 f3 = __half22float2(__builtin_bit_cast(__half2, v.w));
                    a0 += f0.x; a1 += f0.y; a2 += f1.x; a3 += f1.y;
                    a4 += f2.x; a5 += f2.y; a6 += f3.x; a7 += f3.y;
                    x0 += wf.x; x1 += wf.y;
                }
            }
        }
        uint4 xv = h8[(size_t)node * 8 + c];
        float2 f0 = __half22float2(__builtin_bit_cast(__half2, xv.x));
        float2 f1 = __half22float2(__builtin_bit_cast(__half2, xv.y));
        float2 f2 = __half22float2(__builtin_bit_cast(__half2, xv.z));
        float2 f3 = __half22float2(__builtin_bit_cast(__half2, xv.w));
        uint4 sA;
        sA.x = packf2(a0 + f0.x, a1 + f0.y);
        sA.y = packf2(a2 + f1.x, a3 + f1.y);
        sA.z = packf2(a4 + f2.x, a5 + f2.y);
        sA.w = packf2(a6 + f3.x, a7 + f3.y);
        ((uint4*)(&S[tile][m * SROW2]))[c] = sA;
        ((float2*)ea)[(size_t)node * 8 + c] = make_float2(x0, x1);
    }
    __syncthreads();
    if (t >= NT) return;

    int n = lane & 15, quad = lane >> 4;
    half8 bfr[2][2];
#pragma unroll
    for (int kk = 0; kk < 2; kk++)
#pragma unroll
        for (int i = 0; i < 2; i++) {
            int nn = h * 2 + i;
            half8 tmp;
#pragma unroll
            for (int j = 0; j < 8; j++) {
                int kp = kk * 32 + quad * 8 + j;
                tmp[j] = (_Float16)Wom[(128 + kp) * FDIM + nn * 16 + n];
            }
            bfr[kk][i] = tmp;
        }
    float4v acc[2];
#pragma unroll
    for (int i = 0; i < 2; i++) {
        float b = bom[(h * 2 + i) * 16 + n];
#pragma unroll
        for (int r = 0; r < 4; r++) acc[i][r] = b;
    }
    const _Float16* Sr = S[tile];
#pragma unroll
    for (int kk = 0; kk < 2; kk++) {
        half8 a = *(const half8*)(Sr + n * SROW2 + kk * 32 + quad * 8);
#pragma unroll
        for (int i = 0; i < 2; i++)
            acc[i] = __builtin_amdgcn_mfma_f32_16x16x32_f16(a, bfr[kk][i], acc[i], 0, 0, 0);
    }
#pragma unroll
    for (int i = 0; i < 2; i++)
#pragma unroll
        for (int r = 0; r < 4; r++)
            obase16[(size_t)(tb + quad * 4 + r) * FDIM + (h * 2 + i) * 16 + n] =
                __float2half(acc[i][r]);
}

// ---------------- h0/base (VALU, reads fp32 x once) ----------------
__global__ void k_h0base(const float* __restrict__ x, const float* __restrict__ ea,
                         const float* __restrict__ Wnh, const float* __restrict__ bnh,
                         const float* __restrict__ Wmh, const float* __restrict__ bmh,
                         __half* __restrict__ h0out16, __half* __restrict__ base16) {
    __shared__ __align__(16) float sx[4][FDIM];
    __shared__ __align__(16) float sea[4][EDIM];
    int lane = threadIdx.x & 63;
    int wid  = threadIdx.x >> 6;
    float wnh[FDIM], w3[EDIM];
#pragma unroll
    for (int m = 0; m < FDIM; m++) wnh[m] = Wnh[m * FDIM + lane];
    float csum = 0.f;
#pragma unroll
    for (int m = 0; m < EDIM; m++) {
        w3[m] = Wmh[(2 * FDIM + m) * FDIM + lane];
        csum += w3[m];
    }
    float bnhk = bnh[lane], bmhk = bmh[lane];
    int gw = blockIdx.x * 4 + wid;
    int nw = gridDim.x * 4;
    for (int i = gw; i < N_NODES; i += nw) {
        sx[wid][lane] = x[i * FDIM + lane];
        if (lane < EDIM) sea[wid][lane] = ea[i * EDIM + lane];
        float acc0 = bnhk, acc1 = 0.f, acc2 = 0.f, acc3 = 0.f;
        const float4* s4 = (const float4*)sx[wid];
#pragma unroll
        for (int m4 = 0; m4 < FDIM / 4; m4++) {
            float4 v = s4[m4];
            acc0 = fmaf(v.x, wnh[4 * m4 + 0], acc0);
            acc1 = fmaf(v.y, wnh[4 * m4 + 1], acc1);
            acc2 = fmaf(v.z, wnh[4 * m4 + 2], acc2);
            acc3 = fmaf(v.w, wnh[4 * m4 + 3], acc3);
        }
        float h0 = fmaxf((acc0 + acc2) + (acc1 + acc3), 0.f);
        float b0 = h0 + bmhk + csum, b1 = 0.f, b2 = 0.f, b3 = 0.f;
        const float4* e4 = (const float4*)sea[wid];
#pragma unroll
        for (int m4 = 0; m4 < EDIM / 4; m4++) {
            float4 v = e4[m4];
            b0 = fmaf(v.x, w3[4 * m4 + 0], b0);
            b1 = fmaf(v.y, w3[4 * m4 + 1], b1);
            b2 = fmaf(v.z, w3[4 * m4 + 2], b2);
            b3 = fmaf(v.w, w3[4 * m4 + 3], b3);
        }
        h0out16[i * FDIM + lane] = __float2half(h0);
        base16[i * FDIM + lane]  = __float2half((b0 + b2) + (b1 + b3));
    }
}

// out[g] = sum of sc over graph-g nodes + b_out
__global__ void k_pool(const float* __restrict__ sc, const int* __restrict__ batch,
                       const float* __restrict__ b_out, float* __restrict__ out) {
    __shared__ float red[4];
    int g = blockIdx.x, t = threadIdx.x;
    int lo = 0, hi = N_NODES;
    while (lo < hi) { int mid = (lo + hi) >> 1; if (batch[mid] < g) lo = mid + 1; else hi = mid; }
    int lo2 = lo, hi2 = N_NODES;
    while (lo2 < hi2) { int mid = (lo2 + hi2) >> 1; if (batch[mid] < g + 1) lo2 = mid + 1; else hi2 = mid; }
    float s = 0.f;
    for (int i = lo + t; i < lo2; i += 256) s += sc[i];
#pragma unroll
    for (int off = 32; off > 0; off >>= 1) s += __shfl_down(s, off, 64);
    int lane = t & 63, wid = t >> 6;
    if (lane == 0) red[wid] = s;
    __syncthreads();
    if (t == 0) out[g] = red[0] + red[1] + red[2] + red[3] + b_out[0];
}

// ---------------- launcher ----------------

extern "C" void kernel_launch(void* const* d_in, const int* in_sizes, int n_in,
                              void* d_out, int out_size, void* d_ws, size_t ws_size,
                              hipStream_t stream) {
    const float* x         = (const float*)d_in[0];
    const float* edge_attr = (const float*)d_in[1];
    const float* Wnh       = (const float*)d_in[2];
    const float* bnh       = (const float*)d_in[3];
    const float* Wmh       = (const float*)d_in[4];
    const float* bmh       = (const float*)d_in[5];
    const float* Wom       = (const float*)d_in[6];
    const float* bom       = (const float*)d_in[7];
    const float* Wout      = (const float*)d_in[8];
    const float* bout      = (const float*)d_in[9];
    const int*   eidx      = (const int*)d_in[10];
    const int*   batch     = (const int*)d_in[11];
    const int*   srcI = eidx;
    const int*   dstI = eidx + N_EDGES;
    float* out = (float*)d_out;
    (void)in_sizes; (void)n_in; (void)out_size;

    char* w = (char*)d_ws;
    size_t off = 0;
    auto take = [&](size_t b) -> void* {
        void* p = w + off;
        off = (off + b + 255) & ~(size_t)255;
        return p;
    };
    float*  ea     = (float*)take((size_t)N_NODES * EDIM * 4);
    int*    cnt8   = (int*)take((size_t)M8 * 4);
    int*    rowp8  = (int*)take((size_t)(M8 + 1) * 4);
    int*    cur8   = (int*)take((size_t)M8 * 4);
    float*  degf   = (float*)take((size_t)N_NODES * 4);
    int*    colsrc = (int*)take((size_t)N_EDGES * 4);
    int*    coledge= (int*)take((size_t)N_EDGES * 4);
    __half* ea16   = (__half*)take((size_t)N_EDGES * EDIM * 2);
    float*  sc     = (float*)take((size_t)N_NODES * 4);
    int*    blks   = (int*)take((size_t)NB8 * 4);
    int*    boff   = (int*)take((size_t)NB8 * 4);
    __half* x16    = (__half*)take((size_t)N_NODES * FDIM * 2);
    __half* hA16   = (__half*)take((size_t)N_NODES * FDIM * 2);
    __half* hB16   = (__half*)take((size_t)N_NODES * FDIM * 2);
    __half* base16 = (__half*)take((size_t)N_NODES * FDIM * 2);
    __half* obase16= (__half*)take((size_t)N_NODES * FDIM * 2);
    (void)ws_size;

    const int G2 = (NT + 1) / 2;   // 1563 blocks; 4 waves, 2 tiles each

    hipMemsetAsync(cnt8, 0, (size_t)M8 * 4, stream);
    k_count<<<GRID_CF, 256, 0, stream>>>(srcI, dstI, cnt8);
    k_cvt<<<2048, 256, 0, stream>>>(x, x16, edge_attr, ea16);
    k_blksum<<<NB8, 256, 0, stream>>>(cnt8, blks);
    k_scanblk<<<1, 256, 0, stream>>>(blks, boff, rowp8);
    k_rowp<<<NB8, 256, 0, stream>>>(cnt8, boff, rowp8, cur8, degf);
    k_fill<<<GRID_CF, 256, 0, stream>>>(srcI, dstI, cur8, colsrc, coledge);

    k_gxob<<<G2, 256, 0, stream>>>(x16, ea16, rowp8, colsrc, coledge,
                                   Wom, bom, obase16, ea);
    k_h0base<<<2048, 256, 0, stream>>>(x, ea, Wnh, bnh, Wmh, bmh, hA16, base16);

    k_gmv<<<G2, 256, 0, stream>>>(hA16, rowp8, colsrc, base16, degf, Wmh, hB16);
    k_gmv<<<G2, 256, 0, stream>>>(hB16, rowp8, colsrc, base16, degf, Wmh, hA16);
    k_gmv<<<G2, 256, 0, stream>>>(hA16, rowp8, colsrc, base16, degf, Wmh, hB16);

    k_gout<<<G2, 256, 0, stream>>>(hB16, rowp8, colsrc, obase16, degf, Wom, Wout, sc);
    k_pool<<<NGRAPH, 256, 0, stream>>>(sc, batch, bout, out);
}